// Round 1
// baseline (321.281 us; speedup 1.0000x reference)
//
#include <hip/hip_runtime.h>
#include <hip/hip_bf16.h>

// Problem: B=128, T=1024, D=1024, all fp32.
// Key transform: scores = (z_rppg@Wq@Wk^T) . z_eeg  -- never materialize K.
// Pipeline:
//   1) Q  = z_rppg @ Wq            [128,1024]
//   2) Qk = Q @ Wk^T               [128,1024]
//   3) flash pass over z_eeg: Npart[b,blk,:] = sum_t exp(s_t) z[t,:], Zpart = sum exp
//   4) A = sum Npart / sum Zpart
//   5) split-k epilogue partials: fpart = concat(A,z)@Wf_w, mpart = A@Wm_w
//   6) combine: h = relu(z_rppg + (m+Wm_b)*sigmoid(f+Wf_b+bf))

#define BB   128
#define TT   1024
#define DD   1024
#define NT   8     // t-blocks per batch in flash pass
#define KS   8     // split-k factor in epilogue

__global__ __launch_bounds__(256) void k_gemm_ab(const float* __restrict__ X,
                                                 const float* __restrict__ W,
                                                 float* __restrict__ C) {
  // C[b,e] = sum_d X[b,d] * W[d,e];  X:[128,1024], W:[1024,1024]
  const int t = threadIdx.x;
  const int ebase = blockIdx.x * 64;
  const int bbase = blockIdx.y * 16;
  const int e = ebase + (t & 63);
  const int bg = t >> 6;  // 0..3
  __shared__ __align__(16) float Xs[16][64];
  float acc[4] = {0.f, 0.f, 0.f, 0.f};
  for (int k0 = 0; k0 < DD; k0 += 64) {
#pragma unroll
    for (int j = 0; j < 4; ++j) {
      int i = t + 256 * j;
      Xs[i >> 6][i & 63] = X[(size_t)(bbase + (i >> 6)) * DD + k0 + (i & 63)];
    }
    __syncthreads();
#pragma unroll 16
    for (int kk = 0; kk < 64; ++kk) {
      float w = W[(size_t)(k0 + kk) * DD + e];
#pragma unroll
      for (int j = 0; j < 4; ++j) acc[j] = fmaf(Xs[bg + 4 * j][kk], w, acc[j]);
    }
    __syncthreads();
  }
#pragma unroll
  for (int j = 0; j < 4; ++j) C[(size_t)(bbase + bg + 4 * j) * DD + e] = acc[j];
}

__global__ __launch_bounds__(256) void k_gemm_abt(const float* __restrict__ X,
                                                  const float* __restrict__ W,
                                                  float* __restrict__ C) {
  // C[b,d] = sum_e X[b,e] * W[d,e]
  const int t = threadIdx.x;
  const int dbase = blockIdx.x * 64;
  const int bbase = blockIdx.y * 16;
  const int dl = t & 63;
  const int bg = t >> 6;
  __shared__ __align__(16) float Xs[16][64];
  __shared__ __align__(16) float Ws[64][65];
  float acc[4] = {0.f, 0.f, 0.f, 0.f};
  for (int k0 = 0; k0 < DD; k0 += 64) {
#pragma unroll
    for (int j = 0; j < 4; ++j) {
      int i = t + 256 * j;
      Xs[i >> 6][i & 63] = X[(size_t)(bbase + (i >> 6)) * DD + k0 + (i & 63)];
    }
#pragma unroll
    for (int j = 0; j < 16; ++j) {
      int i = t + 256 * j;
      Ws[i >> 6][i & 63] = W[(size_t)(dbase + (i >> 6)) * DD + k0 + (i & 63)];
    }
    __syncthreads();
#pragma unroll 8
    for (int kk = 0; kk < 64; ++kk) {
      float w = Ws[dl][kk];
#pragma unroll
      for (int j = 0; j < 4; ++j) acc[j] = fmaf(Xs[bg + 4 * j][kk], w, acc[j]);
    }
    __syncthreads();
  }
#pragma unroll
  for (int j = 0; j < 4; ++j) C[(size_t)(bbase + bg + 4 * j) * DD + dbase + dl] = acc[j];
}

__global__ __launch_bounds__(256) void k_attn(const float* __restrict__ z_eeg,
                                              const float* __restrict__ Qk,
                                              float* __restrict__ Npart,
                                              float* __restrict__ Zpart) {
  const int t = threadIdx.x;
  const int lane = t & 63;
  const int w = t >> 6;       // wave 0..3
  const int tblk = blockIdx.x;  // 0..NT-1
  const int b = blockIdx.y;     // 0..127

  const float4* qkp = (const float4*)(Qk + (size_t)b * DD);
  float4 qk4[4];
#pragma unroll
  for (int q = 0; q < 4; ++q) qk4[q] = qkp[q * 64 + lane];

  float4 acc[4] = {};
  float zsum = 0.f;
  const float4* zb = (const float4*)(z_eeg + (size_t)b * TT * DD);
  const int row0 = tblk * (TT / NT) + w;

  for (int i = 0; i < (TT / NT) / 4; ++i) {
    const int row = row0 + i * 4;
    const float4* zp = zb + (size_t)row * (DD / 4);
    float4 z4[4];
#pragma unroll
    for (int q = 0; q < 4; ++q) z4[q] = zp[q * 64 + lane];
    float dot = 0.f;
#pragma unroll
    for (int q = 0; q < 4; ++q)
      dot += z4[q].x * qk4[q].x + z4[q].y * qk4[q].y + z4[q].z * qk4[q].z + z4[q].w * qk4[q].w;
#pragma unroll
    for (int off = 32; off >= 1; off >>= 1) dot += __shfl_xor(dot, off);
    float e = __expf(dot * 0.03125f);  // 1/sqrt(1024)
    zsum += e;
#pragma unroll
    for (int q = 0; q < 4; ++q) {
      acc[q].x = fmaf(e, z4[q].x, acc[q].x);
      acc[q].y = fmaf(e, z4[q].y, acc[q].y);
      acc[q].z = fmaf(e, z4[q].z, acc[q].z);
      acc[q].w = fmaf(e, z4[q].w, acc[q].w);
    }
  }

  __shared__ __align__(16) float4 sacc[3][256];
  __shared__ float szw[4];
  if (w > 0) {
#pragma unroll
    for (int q = 0; q < 4; ++q) sacc[w - 1][q * 64 + lane] = acc[q];
  }
  if (lane == 0) szw[w] = zsum;
  __syncthreads();
  if (w == 0) {
    float4* np = (float4*)(Npart + ((size_t)b * NT + tblk) * DD);
#pragma unroll
    for (int q = 0; q < 4; ++q) {
      float4 a = acc[q];
#pragma unroll
      for (int ww = 0; ww < 3; ++ww) {
        float4 s = sacc[ww][q * 64 + lane];
        a.x += s.x; a.y += s.y; a.z += s.z; a.w += s.w;
      }
      np[q * 64 + lane] = a;
    }
    if (lane == 0) Zpart[b * NT + tblk] = szw[0] + szw[1] + szw[2] + szw[3];
  }
}

__global__ __launch_bounds__(256) void k_reduce_a(const float* __restrict__ Npart,
                                                  const float* __restrict__ Zpart,
                                                  float* __restrict__ A) {
  const int idx = blockIdx.x * 256 + threadIdx.x;  // 0..131071
  const int b = idx >> 10;
  const int d = idx & 1023;
  float n = 0.f, z = 0.f;
#pragma unroll
  for (int k = 0; k < NT; ++k) {
    n += Npart[((size_t)b * NT + k) * DD + d];
    z += Zpart[b * NT + k];
  }
  A[idx] = n / z;
}

__device__ __forceinline__ void outer_acc(float4 acc[4], const float4 a, const float4 w) {
  acc[0].x = fmaf(a.x, w.x, acc[0].x); acc[0].y = fmaf(a.x, w.y, acc[0].y);
  acc[0].z = fmaf(a.x, w.z, acc[0].z); acc[0].w = fmaf(a.x, w.w, acc[0].w);
  acc[1].x = fmaf(a.y, w.x, acc[1].x); acc[1].y = fmaf(a.y, w.y, acc[1].y);
  acc[1].z = fmaf(a.y, w.z, acc[1].z); acc[1].w = fmaf(a.y, w.w, acc[1].w);
  acc[2].x = fmaf(a.z, w.x, acc[2].x); acc[2].y = fmaf(a.z, w.y, acc[2].y);
  acc[2].z = fmaf(a.z, w.z, acc[2].z); acc[2].w = fmaf(a.z, w.w, acc[2].w);
  acc[3].x = fmaf(a.w, w.x, acc[3].x); acc[3].y = fmaf(a.w, w.y, acc[3].y);
  acc[3].z = fmaf(a.w, w.z, acc[3].z); acc[3].w = fmaf(a.w, w.w, acc[3].w);
}

__global__ __launch_bounds__(256) void k_epi_partial(const float* __restrict__ A,
                                                     const float* __restrict__ z_rppg,
                                                     const float* __restrict__ Wf_w,
                                                     const float* __restrict__ Wm_w,
                                                     float* __restrict__ fpart,
                                                     float* __restrict__ mpart) {
  const int t = threadIdx.x;
  const int dbase = blockIdx.x * 32;  // 32 d-tiles
  const int ks = blockIdx.y;          // 0..KS-1
  const int bq = t >> 3;              // 0..31 -> b rows bq*4..bq*4+3
  const int dg = t & 7;               // 0..7  -> d cols dg*4..dg*4+3
  __shared__ __align__(16) float Cst[32][132];  // [kk][b], padded
  __shared__ __align__(16) float Ws[32][36];    // [kk][d], padded
  float4 accf[4] = {};
  float4 accm[4] = {};

  // ---- f: k in [ks*256, ks*256+256) of concat([A, z_rppg])
  {
    const float* src = (ks < 4) ? (A + ks * 256) : (z_rppg + ks * 256 - 1024);
    const float* wsrc = Wf_w + (size_t)ks * 256 * DD;
    for (int k0 = 0; k0 < 256; k0 += 32) {
#pragma unroll
      for (int j = 0; j < 16; ++j) {
        int i = t + 256 * j; int bb = i >> 5, c = i & 31;
        Cst[c][bb] = src[(size_t)bb * DD + k0 + c];
      }
#pragma unroll
      for (int j = 0; j < 4; ++j) {
        int i = t + 256 * j; int r = i >> 5, c = i & 31;
        Ws[r][c] = wsrc[(size_t)(k0 + r) * DD + dbase + c];
      }
      __syncthreads();
#pragma unroll
      for (int kk = 0; kk < 32; ++kk) {
        float4 a4 = *(const float4*)&Cst[kk][bq * 4];
        float4 w4 = *(const float4*)&Ws[kk][dg * 4];
        outer_acc(accf, a4, w4);
      }
      __syncthreads();
    }
  }
  // ---- m: k in [ks*128, ks*128+128) of A
  {
    const float* src = A + ks * 128;
    const float* wsrc = Wm_w + (size_t)ks * 128 * DD;
    for (int k0 = 0; k0 < 128; k0 += 32) {
#pragma unroll
      for (int j = 0; j < 16; ++j) {
        int i = t + 256 * j; int bb = i >> 5, c = i & 31;
        Cst[c][bb] = src[(size_t)bb * DD + k0 + c];
      }
#pragma unroll
      for (int j = 0; j < 4; ++j) {
        int i = t + 256 * j; int r = i >> 5, c = i & 31;
        Ws[r][c] = wsrc[(size_t)(k0 + r) * DD + dbase + c];
      }
      __syncthreads();
#pragma unroll
      for (int kk = 0; kk < 32; ++kk) {
        float4 a4 = *(const float4*)&Cst[kk][bq * 4];
        float4 w4 = *(const float4*)&Ws[kk][dg * 4];
        outer_acc(accm, a4, w4);
      }
      __syncthreads();
    }
  }
#pragma unroll
  for (int i = 0; i < 4; ++i) {
    const int b = bq * 4 + i;
    *(float4*)&fpart[(size_t)ks * (BB * DD) + (size_t)b * DD + dbase + dg * 4] = accf[i];
    *(float4*)&mpart[(size_t)ks * (BB * DD) + (size_t)b * DD + dbase + dg * 4] = accm[i];
  }
}

__global__ __launch_bounds__(256) void k_combine(const float* __restrict__ fpart,
                                                 const float* __restrict__ mpart,
                                                 const float* __restrict__ Wf_b,
                                                 const float* __restrict__ bf,
                                                 const float* __restrict__ Wm_b,
                                                 const float* __restrict__ z_rppg,
                                                 float* __restrict__ out) {
  const int idx = blockIdx.x * 256 + threadIdx.x;  // 0..131071
  const int d = idx & 1023;
  float f = Wf_b[d] + bf[d];
  float m = Wm_b[d];
#pragma unroll
  for (int k = 0; k < KS; ++k) {
    f += fpart[(size_t)k * (BB * DD) + idx];
    m += mpart[(size_t)k * (BB * DD) + idx];
  }
  const float g = 1.f / (1.f + __expf(-f));
  const float h = z_rppg[idx] + m * g;
  out[idx] = h > 0.f ? h : 0.f;
}

extern "C" void kernel_launch(void* const* d_in, const int* in_sizes, int n_in,
                              void* d_out, int out_size, void* d_ws, size_t ws_size,
                              hipStream_t stream) {
  const float* z_eeg  = (const float*)d_in[0];
  const float* z_rppg = (const float*)d_in[1];
  const float* Wq     = (const float*)d_in[2];
  const float* Wk     = (const float*)d_in[3];
  const float* Wm_w   = (const float*)d_in[4];
  const float* Wm_b   = (const float*)d_in[5];
  const float* Wf_w   = (const float*)d_in[6];
  const float* Wf_b   = (const float*)d_in[7];
  const float* bf     = (const float*)d_in[8];
  float* out = (float*)d_out;

  float* ws = (float*)d_ws;
  float* Q     = ws;                       // 131072
  float* Qk    = Q + BB * DD;              // 131072
  float* Npart = Qk + BB * DD;             // 128*8*1024 = 1048576
  float* Zpart = Npart + (size_t)BB * NT * DD;  // 1024
  float* A     = Zpart + BB * NT;          // 131072
  float* fpart = Npart;                    // reuse Npart region (consumed by k_reduce_a)
  float* mpart = A + BB * DD;              // 1048576

  // 1) Q = z_rppg @ Wq
  k_gemm_ab<<<dim3(16, 8), 256, 0, stream>>>(z_rppg, Wq, Q);
  // 2) Qk = Q @ Wk^T
  k_gemm_abt<<<dim3(16, 8), 256, 0, stream>>>(Q, Wk, Qk);
  // 3) flash pass over z_eeg
  k_attn<<<dim3(NT, BB), 256, 0, stream>>>(z_eeg, Qk, Npart, Zpart);
  // 4) A = N / Z
  k_reduce_a<<<(BB * DD) / 256, 256, 0, stream>>>(Npart, Zpart, A);
  // 5) epilogue partial GEMMs (fpart overwrites Npart -- Npart already consumed)
  k_epi_partial<<<dim3(32, KS), 256, 0, stream>>>(A, z_rppg, Wf_w, Wm_w, fpart, mpart);
  // 6) combine -> h
  k_combine<<<(BB * DD) / 256, 256, 0, stream>>>(fpart, mpart, Wf_b, bf, Wm_b, z_rppg, out);
}

// Round 2
// 216.881 us; speedup vs baseline: 1.4814x; 1.4814x over previous
//
#include <hip/hip_runtime.h>
#include <hip/hip_bf16.h>

// Problem: B=128, T=1024, D=1024, all fp32.
// Key transform: scores = (z_rppg@Wq@Wk^T) . z_eeg  -- never materialize K.
// Pipeline:
//   1) Qpart  = split-k(4) partials of z_rppg @ Wq        [4,128,1024]
//   2) Qkpart = split-k(4) partials of (sum Qpart) @ Wk^T [4,128,1024]
//   3) flash pass over z_eeg (sums Qkpart + scale inline):
//        Npart[b,blk,:] = sum_t exp(s_t) z[t,:], Zpart = sum exp
//   4) A = sum Npart / sum Zpart
//   5) split-k epilogue partials: fpart = concat(A,z)@Wf_w, mpart = A@Wm_w
//   6) combine: h = relu(z_rppg + (m+Wm_b)*sigmoid(f+Wf_b+bf))

#define BB   128
#define TT   1024
#define DD   1024
#define NT   16    // t-blocks per batch in flash pass (grid = 16*128 = 2048 blocks)
#define KS   8     // split-k factor in epilogue
#define QS   4     // split-k factor in front GEMMs

__global__ __launch_bounds__(256) void k_gemm_ab(const float* __restrict__ X,
                                                 const float* __restrict__ W,
                                                 float* __restrict__ Cpart) {
  // Cpart[p,b,e] = sum_{d in quarter p} X[b,d] * W[d,e]
  const int t = threadIdx.x;
  const int ebase = blockIdx.x * 64;
  const int bbase = blockIdx.y * 16;
  const int p = blockIdx.z;
  const int e = ebase + (t & 63);
  const int bg = t >> 6;  // 0..3
  __shared__ __align__(16) float Xs[16][64];
  float acc[4] = {0.f, 0.f, 0.f, 0.f};
  const int kend = p * 256 + 256;
  for (int k0 = p * 256; k0 < kend; k0 += 64) {
#pragma unroll
    for (int j = 0; j < 4; ++j) {
      int i = t + 256 * j;
      Xs[i >> 6][i & 63] = X[(size_t)(bbase + (i >> 6)) * DD + k0 + (i & 63)];
    }
    __syncthreads();
#pragma unroll 16
    for (int kk = 0; kk < 64; ++kk) {
      float w = W[(size_t)(k0 + kk) * DD + e];
#pragma unroll
      for (int j = 0; j < 4; ++j) acc[j] = fmaf(Xs[bg + 4 * j][kk], w, acc[j]);
    }
    __syncthreads();
  }
#pragma unroll
  for (int j = 0; j < 4; ++j)
    Cpart[(size_t)p * BB * DD + (size_t)(bbase + bg + 4 * j) * DD + e] = acc[j];
}

__global__ __launch_bounds__(256) void k_gemm_abt(const float* __restrict__ Qpart,
                                                  const float* __restrict__ W,
                                                  float* __restrict__ Cpart) {
  // Cpart[p,b,d] = sum_{e in quarter p} Q[b,e] * W[d,e],  Q = sum_pp Qpart[pp]
  const int t = threadIdx.x;
  const int dbase = blockIdx.x * 64;
  const int bbase = blockIdx.y * 16;
  const int p = blockIdx.z;
  const int dl = t & 63;
  const int bg = t >> 6;
  __shared__ __align__(16) float Xs[16][64];
  __shared__ __align__(16) float Ws[64][65];
  float acc[4] = {0.f, 0.f, 0.f, 0.f};
  const int kend = p * 256 + 256;
  for (int k0 = p * 256; k0 < kend; k0 += 64) {
#pragma unroll
    for (int j = 0; j < 4; ++j) {
      int i = t + 256 * j;
      const size_t base = (size_t)(bbase + (i >> 6)) * DD + k0 + (i & 63);
      float v = Qpart[base] + Qpart[base + (size_t)BB * DD] +
                Qpart[base + 2 * (size_t)BB * DD] + Qpart[base + 3 * (size_t)BB * DD];
      Xs[i >> 6][i & 63] = v;
    }
#pragma unroll
    for (int j = 0; j < 16; ++j) {
      int i = t + 256 * j;
      Ws[i >> 6][i & 63] = W[(size_t)(dbase + (i >> 6)) * DD + k0 + (i & 63)];
    }
    __syncthreads();
#pragma unroll 8
    for (int kk = 0; kk < 64; ++kk) {
      float w = Ws[dl][kk];
#pragma unroll
      for (int j = 0; j < 4; ++j) acc[j] = fmaf(Xs[bg + 4 * j][kk], w, acc[j]);
    }
    __syncthreads();
  }
#pragma unroll
  for (int j = 0; j < 4; ++j)
    Cpart[(size_t)p * BB * DD + (size_t)(bbase + bg + 4 * j) * DD + dbase + dl] = acc[j];
}

__global__ __launch_bounds__(256) void k_attn(const float* __restrict__ z_eeg,
                                              const float* __restrict__ Qkpart,
                                              float* __restrict__ Npart,
                                              float* __restrict__ Zpart) {
  const int t = threadIdx.x;
  const int lane = t & 63;
  const int w = t >> 6;         // wave 0..3
  const int tblk = blockIdx.x;  // 0..NT-1
  const int b = blockIdx.y;     // 0..127

  // qk = (sum of 4 partials) * 1/sqrt(1024)
  float4 qk4[4];
#pragma unroll
  for (int q = 0; q < 4; ++q) {
    const float4* p0 = (const float4*)(Qkpart + (size_t)b * DD);
    float4 a = p0[q * 64 + lane];
#pragma unroll
    for (int pp = 1; pp < QS; ++pp) {
      float4 s = ((const float4*)(Qkpart + (size_t)pp * BB * DD + (size_t)b * DD))[q * 64 + lane];
      a.x += s.x; a.y += s.y; a.z += s.z; a.w += s.w;
    }
    a.x *= 0.03125f; a.y *= 0.03125f; a.z *= 0.03125f; a.w *= 0.03125f;
    qk4[q] = a;
  }

  float4 acc[4] = {};
  float zsum = 0.f;
  const float4* zb = (const float4*)(z_eeg + (size_t)b * TT * DD);
  const int row0 = tblk * (TT / NT) + w;  // 64 rows per block

  for (int i = 0; i < 8; ++i) {
    const int rA = row0 + i * 8;
    const int rB = rA + 4;
    const float4* zpA = zb + (size_t)rA * (DD / 4);
    const float4* zpB = zb + (size_t)rB * (DD / 4);
    float4 zA[4], zB[4];
#pragma unroll
    for (int q = 0; q < 4; ++q) zA[q] = zpA[q * 64 + lane];
#pragma unroll
    for (int q = 0; q < 4; ++q) zB[q] = zpB[q * 64 + lane];
    float dotA = 0.f, dotB = 0.f;
#pragma unroll
    for (int q = 0; q < 4; ++q) {
      dotA += zA[q].x * qk4[q].x + zA[q].y * qk4[q].y + zA[q].z * qk4[q].z + zA[q].w * qk4[q].w;
      dotB += zB[q].x * qk4[q].x + zB[q].y * qk4[q].y + zB[q].z * qk4[q].z + zB[q].w * qk4[q].w;
    }
#pragma unroll
    for (int off = 32; off >= 1; off >>= 1) {
      dotA += __shfl_xor(dotA, off);
      dotB += __shfl_xor(dotB, off);
    }
    const float eA = __expf(dotA);
    const float eB = __expf(dotB);
    zsum += eA + eB;
#pragma unroll
    for (int q = 0; q < 4; ++q) {
      acc[q].x = fmaf(eA, zA[q].x, acc[q].x);
      acc[q].y = fmaf(eA, zA[q].y, acc[q].y);
      acc[q].z = fmaf(eA, zA[q].z, acc[q].z);
      acc[q].w = fmaf(eA, zA[q].w, acc[q].w);
      acc[q].x = fmaf(eB, zB[q].x, acc[q].x);
      acc[q].y = fmaf(eB, zB[q].y, acc[q].y);
      acc[q].z = fmaf(eB, zB[q].z, acc[q].z);
      acc[q].w = fmaf(eB, zB[q].w, acc[q].w);
    }
  }

  __shared__ __align__(16) float4 sacc[3][256];
  __shared__ float szw[4];
  if (w > 0) {
#pragma unroll
    for (int q = 0; q < 4; ++q) sacc[w - 1][q * 64 + lane] = acc[q];
  }
  if (lane == 0) szw[w] = zsum;
  __syncthreads();
  if (w == 0) {
    float4* np = (float4*)(Npart + ((size_t)b * NT + tblk) * DD);
#pragma unroll
    for (int q = 0; q < 4; ++q) {
      float4 a = acc[q];
#pragma unroll
      for (int ww = 0; ww < 3; ++ww) {
        float4 s = sacc[ww][q * 64 + lane];
        a.x += s.x; a.y += s.y; a.z += s.z; a.w += s.w;
      }
      np[q * 64 + lane] = a;
    }
    if (lane == 0) Zpart[b * NT + tblk] = szw[0] + szw[1] + szw[2] + szw[3];
  }
}

__global__ __launch_bounds__(256) void k_reduce_a(const float* __restrict__ Npart,
                                                  const float* __restrict__ Zpart,
                                                  float* __restrict__ A) {
  const int idx = blockIdx.x * 256 + threadIdx.x;  // 0..131071
  const int b = idx >> 10;
  const int d = idx & 1023;
  float n = 0.f, z = 0.f;
#pragma unroll
  for (int k = 0; k < NT; ++k) {
    n += Npart[((size_t)b * NT + k) * DD + d];
    z += Zpart[b * NT + k];
  }
  A[idx] = n / z;
}

__device__ __forceinline__ void outer_acc(float4 acc[4], const float4 a, const float4 w) {
  acc[0].x = fmaf(a.x, w.x, acc[0].x); acc[0].y = fmaf(a.x, w.y, acc[0].y);
  acc[0].z = fmaf(a.x, w.z, acc[0].z); acc[0].w = fmaf(a.x, w.w, acc[0].w);
  acc[1].x = fmaf(a.y, w.x, acc[1].x); acc[1].y = fmaf(a.y, w.y, acc[1].y);
  acc[1].z = fmaf(a.y, w.z, acc[1].z); acc[1].w = fmaf(a.y, w.w, acc[1].w);
  acc[2].x = fmaf(a.z, w.x, acc[2].x); acc[2].y = fmaf(a.z, w.y, acc[2].y);
  acc[2].z = fmaf(a.z, w.z, acc[2].z); acc[2].w = fmaf(a.z, w.w, acc[2].w);
  acc[3].x = fmaf(a.w, w.x, acc[3].x); acc[3].y = fmaf(a.w, w.y, acc[3].y);
  acc[3].z = fmaf(a.w, w.z, acc[3].z); acc[3].w = fmaf(a.w, w.w, acc[3].w);
}

__global__ __launch_bounds__(256) void k_epi_partial(const float* __restrict__ A,
                                                     const float* __restrict__ z_rppg,
                                                     const float* __restrict__ Wf_w,
                                                     const float* __restrict__ Wm_w,
                                                     float* __restrict__ fpart,
                                                     float* __restrict__ mpart) {
  const int t = threadIdx.x;
  const int dbase = blockIdx.x * 32;  // 32 d-tiles
  const int ks = blockIdx.y;          // 0..KS-1
  const int bq = t >> 3;              // 0..31 -> b rows bq*4..bq*4+3
  const int dg = t & 7;               // 0..7  -> d cols dg*4..dg*4+3
  __shared__ __align__(16) float Cst[32][132];  // [kk][b], padded
  __shared__ __align__(16) float Ws[32][36];    // [kk][d], padded
  float4 accf[4] = {};
  float4 accm[4] = {};

  // ---- f: k in [ks*256, ks*256+256) of concat([A, z_rppg])
  {
    const float* src = (ks < 4) ? (A + ks * 256) : (z_rppg + ks * 256 - 1024);
    const float* wsrc = Wf_w + (size_t)ks * 256 * DD;
    for (int k0 = 0; k0 < 256; k0 += 32) {
#pragma unroll
      for (int j = 0; j < 16; ++j) {
        int i = t + 256 * j; int bb = i >> 5, c = i & 31;
        Cst[c][bb] = src[(size_t)bb * DD + k0 + c];
      }
#pragma unroll
      for (int j = 0; j < 4; ++j) {
        int i = t + 256 * j; int r = i >> 5, c = i & 31;
        Ws[r][c] = wsrc[(size_t)(k0 + r) * DD + dbase + c];
      }
      __syncthreads();
#pragma unroll
      for (int kk = 0; kk < 32; ++kk) {
        float4 a4 = *(const float4*)&Cst[kk][bq * 4];
        float4 w4 = *(const float4*)&Ws[kk][dg * 4];
        outer_acc(accf, a4, w4);
      }
      __syncthreads();
    }
  }
  // ---- m: k in [ks*128, ks*128+128) of A
  {
    const float* src = A + ks * 128;
    const float* wsrc = Wm_w + (size_t)ks * 128 * DD;
    for (int k0 = 0; k0 < 128; k0 += 32) {
#pragma unroll
      for (int j = 0; j < 16; ++j) {
        int i = t + 256 * j; int bb = i >> 5, c = i & 31;
        Cst[c][bb] = src[(size_t)bb * DD + k0 + c];
      }
#pragma unroll
      for (int j = 0; j < 4; ++j) {
        int i = t + 256 * j; int r = i >> 5, c = i & 31;
        Ws[r][c] = wsrc[(size_t)(k0 + r) * DD + dbase + c];
      }
      __syncthreads();
#pragma unroll
      for (int kk = 0; kk < 32; ++kk) {
        float4 a4 = *(const float4*)&Cst[kk][bq * 4];
        float4 w4 = *(const float4*)&Ws[kk][dg * 4];
        outer_acc(accm, a4, w4);
      }
      __syncthreads();
    }
  }
#pragma unroll
  for (int i = 0; i < 4; ++i) {
    const int b = bq * 4 + i;
    *(float4*)&fpart[(size_t)ks * (BB * DD) + (size_t)b * DD + dbase + dg * 4] = accf[i];
    *(float4*)&mpart[(size_t)ks * (BB * DD) + (size_t)b * DD + dbase + dg * 4] = accm[i];
  }
}

__global__ __launch_bounds__(256) void k_combine(const float* __restrict__ fpart,
                                                 const float* __restrict__ mpart,
                                                 const float* __restrict__ Wf_b,
                                                 const float* __restrict__ bf,
                                                 const float* __restrict__ Wm_b,
                                                 const float* __restrict__ z_rppg,
                                                 float* __restrict__ out) {
  const int idx = blockIdx.x * 256 + threadIdx.x;  // 0..131071
  const int d = idx & 1023;
  float f = Wf_b[d] + bf[d];
  float m = Wm_b[d];
#pragma unroll
  for (int k = 0; k < KS; ++k) {
    f += fpart[(size_t)k * (BB * DD) + idx];
    m += mpart[(size_t)k * (BB * DD) + idx];
  }
  const float g = 1.f / (1.f + __expf(-f));
  const float h = z_rppg[idx] + m * g;
  out[idx] = h > 0.f ? h : 0.f;
}

extern "C" void kernel_launch(void* const* d_in, const int* in_sizes, int n_in,
                              void* d_out, int out_size, void* d_ws, size_t ws_size,
                              hipStream_t stream) {
  const float* z_eeg  = (const float*)d_in[0];
  const float* z_rppg = (const float*)d_in[1];
  const float* Wq     = (const float*)d_in[2];
  const float* Wk     = (const float*)d_in[3];
  const float* Wm_w   = (const float*)d_in[4];
  const float* Wm_b   = (const float*)d_in[5];
  const float* Wf_w   = (const float*)d_in[6];
  const float* Wf_b   = (const float*)d_in[7];
  const float* bf     = (const float*)d_in[8];
  float* out = (float*)d_out;

  float* ws = (float*)d_ws;
  float* Qpart  = ws;                              // 4*128*1024 = 524288
  float* Qkpart = Qpart + (size_t)QS * BB * DD;    // 524288
  float* Npart  = Qkpart + (size_t)QS * BB * DD;   // 128*16*1024 = 2097152
  float* Zpart  = Npart + (size_t)BB * NT * DD;    // 2048
  float* A      = Zpart + BB * NT;                 // 131072
  float* fpart  = Npart;                           // reuse first 4 MB of Npart
  float* mpart  = Npart + (size_t)KS * BB * DD;    // reuse second 4 MB of Npart

  // 1) Qpart = split-k partials of z_rppg @ Wq
  k_gemm_ab<<<dim3(16, 8, QS), 256, 0, stream>>>(z_rppg, Wq, Qpart);
  // 2) Qkpart = split-k partials of Q @ Wk^T (sums Qpart while staging)
  k_gemm_abt<<<dim3(16, 8, QS), 256, 0, stream>>>(Qpart, Wk, Qkpart);
  // 3) flash pass over z_eeg (sums Qkpart + scales inline)
  k_attn<<<dim3(NT, BB), 256, 0, stream>>>(z_eeg, Qkpart, Npart, Zpart);
  // 4) A = N / Z
  k_reduce_a<<<(BB * DD) / 256, 256, 0, stream>>>(Npart, Zpart, A);
  // 5) epilogue partial GEMMs (fpart/mpart overwrite Npart -- already consumed)
  k_epi_partial<<<dim3(32, KS), 256, 0, stream>>>(A, z_rppg, Wf_w, Wm_w, fpart, mpart);
  // 6) combine -> h
  k_combine<<<(BB * DD) / 256, 256, 0, stream>>>(fpart, mpart, Wf_b, bf, Wm_b, z_rppg, out);
}